// Round 4
// baseline (1746.803 us; speedup 1.0000x reference)
//
#include <hip/hip_runtime.h>

#define N_NODES 100000
#define N_EDGES 3200000
#define NB 391            // ceil(100000/256) buckets of 256 dst nodes
#define BUCKET_SHIFT 8
#define BUCKET_NODES 256
#define CHUNK 8192        // edges per partition block
#define NPART 391         // ceil(N_EDGES / CHUNK)

// ---------------------------------------------------------------------------
// Kernel A: feat = node_feat @ Wfc.T  (N x 64), el/er = sum(feat*attn, -1)
// ---------------------------------------------------------------------------
__global__ __launch_bounds__(256) void node_proj(
    const float* __restrict__ node_feat,
    const float* __restrict__ Wfc,
    const float* __restrict__ attn_l,
    const float* __restrict__ attn_r,
    float* __restrict__ feat,
    float* __restrict__ el,
    float* __restrict__ er)
{
    __shared__ float T2[32 * 64 * 4];   // T2[(k4*64 + j)*4 + kk] = Wfc[j*128 + k4*4+kk]
    const int tid = threadIdx.x;
    for (int i = tid; i < 64 * 128; i += 256) {
        int j = i >> 7, k = i & 127;
        T2[((k >> 2) * 64 + j) * 4 + (k & 3)] = Wfc[i];
    }
    __syncthreads();

    const int lane = tid & 63;
    const float al = attn_l[lane];
    const float ar = attn_r[lane];
    const int gw = blockIdx.x * 4 + (tid >> 6);
    const int nw = gridDim.x * 4;
    const float4* __restrict__ T2v = (const float4*)T2;

    for (int g = gw; g * 4 < N_NODES; g += nw) {
        const int n0 = g * 4;
        const float4* __restrict__ x0 = (const float4*)(node_feat + (size_t)(n0 + 0) * 128);
        const float4* __restrict__ x1 = (const float4*)(node_feat + (size_t)(n0 + 1) * 128);
        const float4* __restrict__ x2 = (const float4*)(node_feat + (size_t)(n0 + 2) * 128);
        const float4* __restrict__ x3 = (const float4*)(node_feat + (size_t)(n0 + 3) * 128);

        float acc0 = 0.f, acc1 = 0.f, acc2 = 0.f, acc3 = 0.f;
        #pragma unroll 8
        for (int k4 = 0; k4 < 32; ++k4) {
            const float4 v0 = x0[k4], v1 = x1[k4], v2 = x2[k4], v3 = x3[k4];
            const float4 w = T2v[k4 * 64 + lane];
            acc0 = fmaf(v0.x, w.x, acc0); acc0 = fmaf(v0.y, w.y, acc0);
            acc0 = fmaf(v0.z, w.z, acc0); acc0 = fmaf(v0.w, w.w, acc0);
            acc1 = fmaf(v1.x, w.x, acc1); acc1 = fmaf(v1.y, w.y, acc1);
            acc1 = fmaf(v1.z, w.z, acc1); acc1 = fmaf(v1.w, w.w, acc1);
            acc2 = fmaf(v2.x, w.x, acc2); acc2 = fmaf(v2.y, w.y, acc2);
            acc2 = fmaf(v2.z, w.z, acc2); acc2 = fmaf(v2.w, w.w, acc2);
            acc3 = fmaf(v3.x, w.x, acc3); acc3 = fmaf(v3.y, w.y, acc3);
            acc3 = fmaf(v3.z, w.z, acc3); acc3 = fmaf(v3.w, w.w, acc3);
        }

        feat[(size_t)(n0 + 0) * 64 + lane] = acc0;
        feat[(size_t)(n0 + 1) * 64 + lane] = acc1;
        feat[(size_t)(n0 + 2) * 64 + lane] = acc2;
        feat[(size_t)(n0 + 3) * 64 + lane] = acc3;

        const float accs[4] = {acc0, acc1, acc2, acc3};
        #pragma unroll
        for (int i = 0; i < 4; ++i) {
            float vl = accs[i] * al;
            float vr = accs[i] * ar;
            #pragma unroll
            for (int off = 8; off >= 1; off >>= 1) {
                vl += __shfl_xor(vl, off);
                vr += __shfl_xor(vr, off);
            }
            if ((lane & 15) == 0) {
                el[(size_t)(n0 + i) * 4 + (lane >> 4)] = vl;
                er[(size_t)(n0 + i) * 4 + (lane >> 4)] = vr;
            }
        }
    }
}

// ---------------------------------------------------------------------------
// Bucket histogram: LDS-aggregated, ~200K device atomics instead of 3.2M
// ---------------------------------------------------------------------------
__global__ __launch_bounds__(256) void bhist(const int* __restrict__ dst,
                                             int* __restrict__ totals)
{
    __shared__ int h[NB];
    for (int i = threadIdx.x; i < NB; i += 256) h[i] = 0;
    __syncthreads();
    const int stride = gridDim.x * 256;
    for (int e = blockIdx.x * 256 + threadIdx.x; e < N_EDGES; e += stride)
        atomicAdd(&h[dst[e] >> BUCKET_SHIFT], 1);
    __syncthreads();
    for (int i = threadIdx.x; i < NB; i += 256)
        if (h[i]) atomicAdd(&totals[i], h[i]);
}

// ---------------------------------------------------------------------------
// Scan of 391 bucket totals (single block), init cursor = base
// ---------------------------------------------------------------------------
__global__ __launch_bounds__(512) void bscan(const int* __restrict__ totals,
                                             int* __restrict__ base,
                                             int* __restrict__ cursor)
{
    __shared__ int lds[512];
    const int t = threadIdx.x;
    const int v = (t < NB) ? totals[t] : 0;
    lds[t] = v;
    __syncthreads();
    int x = v;
    for (int off = 1; off < 512; off <<= 1) {
        int y = (t >= off) ? lds[t - off] : 0;
        __syncthreads();
        x += y;
        lds[t] = x;
        __syncthreads();
    }
    if (t < NB) {
        base[t] = x - v;         // exclusive
        cursor[t] = x - v;
        if (t == NB - 1) base[NB] = x;   // total
    }
}

// ---------------------------------------------------------------------------
// Partition: stage chunk in LDS, per-block bucket reservation (~150K device
// atomics total), write packed 8B payload (src | dst_local<<17, eid).
// ---------------------------------------------------------------------------
__global__ __launch_bounds__(256) void partition(
    const int* __restrict__ src,
    const int* __restrict__ dst,
    int* __restrict__ cursor,
    unsigned long long* __restrict__ buf)
{
    __shared__ int ldst[CHUNK];
    __shared__ int lbase[NB];
    __shared__ int lcnt[NB];
    const int e0 = blockIdx.x * CHUNK;
    const int n = min(CHUNK, N_EDGES - e0);
    for (int i = threadIdx.x; i < NB; i += 256) lcnt[i] = 0;
    __syncthreads();
    for (int i = threadIdx.x; i < n; i += 256) {
        const int d = dst[e0 + i];
        ldst[i] = d;
        atomicAdd(&lcnt[d >> BUCKET_SHIFT], 1);
    }
    __syncthreads();
    for (int b = threadIdx.x; b < NB; b += 256) {
        const int c = lcnt[b];
        lbase[b] = c ? atomicAdd(&cursor[b], c) : 0;
        lcnt[b] = 0;
    }
    __syncthreads();
    for (int i = threadIdx.x; i < n; i += 256) {
        const int d = ldst[i];
        const int b = d >> BUCKET_SHIFT;
        const int r = atomicAdd(&lcnt[b], 1);
        const unsigned w0 = (unsigned)(src[e0 + i]) | ((unsigned)(d & (BUCKET_NODES - 1)) << 17);
        buf[lbase[b] + r] = (unsigned long long)w0 |
                            ((unsigned long long)(unsigned)(e0 + i) << 32);
    }
}

// ---------------------------------------------------------------------------
// Aggregate: one block per bucket (256 dst nodes). LDS acc[node][68]
// (64 features + 4 softmax denominators), LDS f32 atomics (conflict-free by
// lane). 64-edge batched payload prefetch + shfl broadcast for MLP.
// ---------------------------------------------------------------------------
__global__ __launch_bounds__(256) void aggregate(
    const float* __restrict__ edge_feat,
    const float* __restrict__ We,
    const float* __restrict__ el,
    const float* __restrict__ er,
    const int* __restrict__ base,
    const unsigned long long* __restrict__ buf,
    const float* __restrict__ feat,
    float* __restrict__ rst)
{
    __shared__ float acc[BUCKET_NODES][68];
    __shared__ float lder[BUCKET_NODES * 4];
    const int b = blockIdx.x;
    const int node0 = b * BUCKET_NODES;
    const int nn = min(BUCKET_NODES, N_NODES - node0);
    const int tid = threadIdx.x;

    for (int i = tid; i < BUCKET_NODES * 68; i += 256) ((float*)acc)[i] = 0.f;
    for (int i = tid; i < nn * 4; i += 256) lder[i] = er[(size_t)node0 * 4 + i];
    __syncthreads();

    const int lane = tid & 63;
    const int wid = tid >> 6;
    const int c = lane >> 4;
    const float w0 = We[c * 4 + 0], w1 = We[c * 4 + 1];
    const float w2 = We[c * 4 + 2], w3 = We[c * 4 + 3];

    const int start = base[b];
    const int end = base[b + 1];

    for (int batch = start + wid * 64; batch < end; batch += 4 * 64) {
        const int n = min(64, end - batch);
        unsigned long long p = 0;
        if (lane < n) p = buf[batch + lane];
        const unsigned pw = (unsigned)p;
        const int peid = (int)(unsigned)(p >> 32);
        for (int i = 0; i < n; ++i) {
            const unsigned wp = __shfl(pw, i);
            const int eid = __shfl(peid, i);
            const int si = (int)(wp & 0x1FFFFu);
            const int dl = (int)((wp >> 17) & 0xFFu);
            const float4 ef = ((const float4*)edge_feat)[eid];
            const float lc = el[(size_t)si * 4 + c];
            const float rc = lder[dl * 4 + c];
            float t = lc + rc;
            t = t > 0.f ? t : 0.2f * t;
            const float ee = __expf(t * (w0 * ef.x + w1 * ef.y + w2 * ef.z + w3 * ef.w));
            const float fv = feat[(size_t)si * 64 + lane];
            atomicAdd(&acc[dl][lane], ee * fv);
            if ((lane & 15) == 0) atomicAdd(&acc[dl][64 + c], ee);
        }
    }
    __syncthreads();

    for (int i = tid; i < nn * 64; i += 256) {
        const int nl = i >> 6, j = i & 63;
        const float s = acc[nl][64 + (j >> 4)];
        rst[(size_t)(node0 + nl) * 64 + j] = (s != 0.f) ? acc[nl][j] / s : 0.f;
    }
}

// ---------------------------------------------------------------------------
extern "C" void kernel_launch(void* const* d_in, const int* in_sizes, int n_in,
                              void* d_out, int out_size, void* d_ws, size_t ws_size,
                              hipStream_t stream)
{
    const float* node_feat = (const float*)d_in[0];
    const float* edge_feat = (const float*)d_in[1];
    const int*   src       = (const int*)d_in[2];
    const int*   dst       = (const int*)d_in[3];
    const float* Wfc       = (const float*)d_in[4];
    const float* We        = (const float*)d_in[5];
    const float* attn_l    = (const float*)d_in[6];
    const float* attn_r    = (const float*)d_in[7];
    float* rst = (float*)d_out;

    char* ws = (char*)d_ws;
    float* feat    = (float*)(ws);                    // 25,600,000 B
    float* el      = (float*)(ws + 25600000);         //  1,600,000 B
    float* er      = (float*)(ws + 27200000);         //  1,600,000 B
    int*   totals  = (int*)  (ws + 28800000);         //      1,564 B (pad 4K)
    int*   base    = (int*)  (ws + 28804096);         //      1,568 B (pad 4K)
    int*   cursor  = (int*)  (ws + 28808192);         //      1,564 B (pad 4K)
    unsigned long long* buf = (unsigned long long*)(ws + 28812288); // 25,600,000 B
                                                      // total ~54.4 MB

    hipMemsetAsync(totals, 0, NB * sizeof(int), stream);

    node_proj<<<1250, 256, 0, stream>>>(node_feat, Wfc, attn_l, attn_r, feat, el, er);
    bhist<<<512, 256, 0, stream>>>(dst, totals);
    bscan<<<1, 512, 0, stream>>>(totals, base, cursor);
    partition<<<NPART, 256, 0, stream>>>(src, dst, cursor, buf);
    aggregate<<<NB, 256, 0, stream>>>(edge_feat, We, el, er, base, buf, feat, rst);
}

// Round 5
// 423.763 us; speedup vs baseline: 4.1221x; 4.1221x over previous
//
#include <hip/hip_runtime.h>

#define N_NODES 100000
#define N_EDGES 3200000
#define BUCKET_SHIFT 7
#define BUCKET_NODES 128
#define NB 782            // ceil(100000/128) buckets of 128 dst nodes
#define CHUNK 8192        // edges per partition block
#define NPART 391         // ceil(N_EDGES / CHUNK)
#define FS_CAP 6144       // finesort LDS staging capacity (mean bucket = 4096, >30 sigma)

__device__ __forceinline__ unsigned short f2bf(float f) {
    unsigned u = __float_as_uint(f);
    unsigned r = (u + 0x7FFFu + ((u >> 16) & 1u)) >> 16;   // RNE
    return (unsigned short)r;
}
__device__ __forceinline__ float bf2f(unsigned short h) {
    return __uint_as_float(((unsigned)h) << 16);
}

// ---------------------------------------------------------------------------
// Kernel A: feat(bf16) = node_feat @ Wfc.T, el/er = sum(feat*attn, -1)
// ---------------------------------------------------------------------------
__global__ __launch_bounds__(256) void node_proj(
    const float* __restrict__ node_feat,
    const float* __restrict__ Wfc,
    const float* __restrict__ attn_l,
    const float* __restrict__ attn_r,
    unsigned short* __restrict__ featb,
    float* __restrict__ el,
    float* __restrict__ er)
{
    __shared__ float T2[32 * 64 * 4];   // T2[(k4*64 + j)*4 + kk] = Wfc[j*128 + k4*4+kk]
    const int tid = threadIdx.x;
    for (int i = tid; i < 64 * 128; i += 256) {
        int j = i >> 7, k = i & 127;
        T2[((k >> 2) * 64 + j) * 4 + (k & 3)] = Wfc[i];
    }
    __syncthreads();

    const int lane = tid & 63;
    const float al = attn_l[lane];
    const float ar = attn_r[lane];
    const int gw = blockIdx.x * 4 + (tid >> 6);
    const int nw = gridDim.x * 4;
    const float4* __restrict__ T2v = (const float4*)T2;

    for (int g = gw; g * 4 < N_NODES; g += nw) {
        const int n0 = g * 4;
        const float4* __restrict__ x0 = (const float4*)(node_feat + (size_t)(n0 + 0) * 128);
        const float4* __restrict__ x1 = (const float4*)(node_feat + (size_t)(n0 + 1) * 128);
        const float4* __restrict__ x2 = (const float4*)(node_feat + (size_t)(n0 + 2) * 128);
        const float4* __restrict__ x3 = (const float4*)(node_feat + (size_t)(n0 + 3) * 128);

        float acc0 = 0.f, acc1 = 0.f, acc2 = 0.f, acc3 = 0.f;
        #pragma unroll 8
        for (int k4 = 0; k4 < 32; ++k4) {
            const float4 v0 = x0[k4], v1 = x1[k4], v2 = x2[k4], v3 = x3[k4];
            const float4 w = T2v[k4 * 64 + lane];
            acc0 = fmaf(v0.x, w.x, acc0); acc0 = fmaf(v0.y, w.y, acc0);
            acc0 = fmaf(v0.z, w.z, acc0); acc0 = fmaf(v0.w, w.w, acc0);
            acc1 = fmaf(v1.x, w.x, acc1); acc1 = fmaf(v1.y, w.y, acc1);
            acc1 = fmaf(v1.z, w.z, acc1); acc1 = fmaf(v1.w, w.w, acc1);
            acc2 = fmaf(v2.x, w.x, acc2); acc2 = fmaf(v2.y, w.y, acc2);
            acc2 = fmaf(v2.z, w.z, acc2); acc2 = fmaf(v2.w, w.w, acc2);
            acc3 = fmaf(v3.x, w.x, acc3); acc3 = fmaf(v3.y, w.y, acc3);
            acc3 = fmaf(v3.z, w.z, acc3); acc3 = fmaf(v3.w, w.w, acc3);
        }

        featb[(size_t)(n0 + 0) * 64 + lane] = f2bf(acc0);
        featb[(size_t)(n0 + 1) * 64 + lane] = f2bf(acc1);
        featb[(size_t)(n0 + 2) * 64 + lane] = f2bf(acc2);
        featb[(size_t)(n0 + 3) * 64 + lane] = f2bf(acc3);

        const float accs[4] = {acc0, acc1, acc2, acc3};
        #pragma unroll
        for (int i = 0; i < 4; ++i) {
            float vl = accs[i] * al;
            float vr = accs[i] * ar;
            #pragma unroll
            for (int off = 8; off >= 1; off >>= 1) {
                vl += __shfl_xor(vl, off);
                vr += __shfl_xor(vr, off);
            }
            if ((lane & 15) == 0) {
                el[(size_t)(n0 + i) * 4 + (lane >> 4)] = vl;
                er[(size_t)(n0 + i) * 4 + (lane >> 4)] = vr;
            }
        }
    }
}

// ---------------------------------------------------------------------------
// Bucket histogram: LDS-aggregated
// ---------------------------------------------------------------------------
__global__ __launch_bounds__(256) void bhist(const int* __restrict__ dst,
                                             int* __restrict__ totals)
{
    __shared__ int h[NB];
    for (int i = threadIdx.x; i < NB; i += 256) h[i] = 0;
    __syncthreads();
    const int stride = gridDim.x * 256;
    for (int e = blockIdx.x * 256 + threadIdx.x; e < N_EDGES; e += stride)
        atomicAdd(&h[dst[e] >> BUCKET_SHIFT], 1);
    __syncthreads();
    for (int i = threadIdx.x; i < NB; i += 256)
        if (h[i]) atomicAdd(&totals[i], h[i]);
}

// ---------------------------------------------------------------------------
// Scan of NB bucket totals: single wave, shfl scan with running carry
// ---------------------------------------------------------------------------
__global__ __launch_bounds__(64) void bscan(const int* __restrict__ totals,
                                            int* __restrict__ base,
                                            int* __restrict__ cursor)
{
    const int lane = threadIdx.x;
    int carry = 0;
    for (int ch = 0; ch < NB; ch += 64) {
        const int idx = ch + lane;
        const int v = (idx < NB) ? totals[idx] : 0;
        int x = v;
        #pragma unroll
        for (int off = 1; off < 64; off <<= 1) {
            int y = __shfl_up(x, off);
            if (lane >= off) x += y;
        }
        const int excl = x - v + carry;
        if (idx < NB) { base[idx] = excl; cursor[idx] = excl; }
        carry += __shfl(x, 63);
    }
    if (lane == 0) base[NB] = carry;
}

// ---------------------------------------------------------------------------
// Partition: stage chunk dsts in LDS, per-block bucket reservation,
// write packed 8B payload (src | dst_local<<17, eid) into bucket regions.
// ---------------------------------------------------------------------------
__global__ __launch_bounds__(256) void partition(
    const int* __restrict__ src,
    const int* __restrict__ dst,
    int* __restrict__ cursor,
    unsigned long long* __restrict__ buf)
{
    __shared__ int ldst[CHUNK];
    __shared__ int lbase[NB];
    __shared__ int lcnt[NB];
    const int e0 = blockIdx.x * CHUNK;
    const int n = min(CHUNK, N_EDGES - e0);
    for (int i = threadIdx.x; i < NB; i += 256) lcnt[i] = 0;
    __syncthreads();
    for (int i = threadIdx.x; i < n; i += 256) {
        const int d = dst[e0 + i];
        ldst[i] = d;
        atomicAdd(&lcnt[d >> BUCKET_SHIFT], 1);
    }
    __syncthreads();
    for (int b = threadIdx.x; b < NB; b += 256) {
        const int c = lcnt[b];
        lbase[b] = c ? atomicAdd(&cursor[b], c) : 0;
        lcnt[b] = 0;
    }
    __syncthreads();
    for (int i = threadIdx.x; i < n; i += 256) {
        const int d = ldst[i];
        const int b = d >> BUCKET_SHIFT;
        const int r = atomicAdd(&lcnt[b], 1);
        const unsigned w0 = (unsigned)(src[e0 + i]) |
                            ((unsigned)(d & (BUCKET_NODES - 1)) << 17);
        buf[lbase[b] + r] = (unsigned long long)w0 |
                            ((unsigned long long)(unsigned)(e0 + i) << 32);
    }
}

// ---------------------------------------------------------------------------
// Finesort: one block per bucket. Stage whole bucket in LDS, counting-sort
// by dst-local IN PLACE in buf, emit exact per-node CSR offsets.
// ---------------------------------------------------------------------------
__global__ __launch_bounds__(256) void finesort(
    const int* __restrict__ base,
    unsigned long long* __restrict__ buf,
    int* __restrict__ node_off)
{
    __shared__ unsigned long long stage[FS_CAP];
    __shared__ int hist[BUCKET_NODES];
    __shared__ int cur[BUCKET_NODES];
    const int b = blockIdx.x;
    const int s = base[b];
    int cnt = base[b + 1] - s;
    if (cnt > FS_CAP) cnt = FS_CAP;   // unreachable for this dataset; safety
    const int tid = threadIdx.x;
    if (tid < BUCKET_NODES) hist[tid] = 0;
    __syncthreads();
    for (int i = tid; i < cnt; i += 256) {
        const unsigned long long p = buf[s + i];
        stage[i] = p;
        atomicAdd(&hist[((unsigned)p >> 17) & (BUCKET_NODES - 1)], 1);
    }
    __syncthreads();
    if (tid < 64) {
        int carry = 0;
        for (int ch = 0; ch < BUCKET_NODES; ch += 64) {
            const int v = hist[ch + tid];
            int x = v;
            #pragma unroll
            for (int off = 1; off < 64; off <<= 1) {
                int y = __shfl_up(x, off);
                if (tid >= off) x += y;
            }
            const int excl = x - v + carry;
            cur[ch + tid] = excl;
            const int node = b * BUCKET_NODES + ch + tid;
            if (node < N_NODES) node_off[node] = s + excl;
            carry += __shfl(x, 63);
        }
        if (tid == 0 && b == NB - 1) node_off[N_NODES] = N_EDGES;
    }
    __syncthreads();
    for (int i = tid; i < cnt; i += 256) {
        const unsigned long long p = stage[i];
        const int dl = ((unsigned)p >> 17) & (BUCKET_NODES - 1);
        const int r = atomicAdd(&cur[dl], 1);
        buf[s + r] = p;
    }
}

// ---------------------------------------------------------------------------
// Aggregate: one wave per dst node (100K waves). Lane j -> (c=j>>4, f=j&15).
// Sequential payload reads, register accumulation, single coalesced store.
// ---------------------------------------------------------------------------
__global__ __launch_bounds__(256) void aggregate(
    const float* __restrict__ edge_feat,
    const float* __restrict__ We,
    const float* __restrict__ el,
    const float* __restrict__ er,
    const int* __restrict__ node_off,
    const unsigned long long* __restrict__ buf,
    const unsigned short* __restrict__ featb,
    float* __restrict__ rst)
{
    const int node = (int)((blockIdx.x * 256 + threadIdx.x) >> 6);
    const int lane = threadIdx.x & 63;
    if (node >= N_NODES) return;
    const int c = lane >> 4;

    const float w0 = We[c * 4 + 0], w1 = We[c * 4 + 1];
    const float w2 = We[c * 4 + 2], w3 = We[c * 4 + 3];
    const float rc = er[(size_t)node * 4 + c];
    const int start = node_off[node];
    const int end = node_off[node + 1];

    float acc = 0.f, ssum = 0.f;
    for (int bat = start; bat < end; bat += 64) {
        const int n = min(64, end - bat);
        unsigned long long p = 0;
        if (lane < n) p = buf[bat + lane];
        const unsigned pw = (unsigned)p;
        const int peid = (int)(unsigned)(p >> 32);
        for (int i = 0; i < n; ++i) {
            const unsigned wp = __shfl(pw, i);
            const int eid = __shfl(peid, i);
            const int si = (int)(wp & 0x1FFFFu);
            const float4 ef = ((const float4*)edge_feat)[eid];
            const float lc = el[(size_t)si * 4 + c];
            float t = lc + rc;
            t = t > 0.f ? t : 0.2f * t;
            const float ee = __expf(t * (w0 * ef.x + w1 * ef.y + w2 * ef.z + w3 * ef.w));
            const float fv = bf2f(featb[(size_t)si * 64 + lane]);
            acc = fmaf(ee, fv, acc);
            ssum += ee;
        }
    }
    rst[(size_t)node * 64 + lane] = (end > start) ? acc / ssum : 0.f;
}

// ---------------------------------------------------------------------------
extern "C" void kernel_launch(void* const* d_in, const int* in_sizes, int n_in,
                              void* d_out, int out_size, void* d_ws, size_t ws_size,
                              hipStream_t stream)
{
    const float* node_feat = (const float*)d_in[0];
    const float* edge_feat = (const float*)d_in[1];
    const int*   src       = (const int*)d_in[2];
    const int*   dst       = (const int*)d_in[3];
    const float* Wfc       = (const float*)d_in[4];
    const float* We        = (const float*)d_in[5];
    const float* attn_l    = (const float*)d_in[6];
    const float* attn_r    = (const float*)d_in[7];
    float* rst = (float*)d_out;

    char* ws = (char*)d_ws;
    unsigned short* featb = (unsigned short*)(ws);        // 12,800,000 B
    float* el      = (float*)(ws + 12800000);             //  1,600,000 B
    float* er      = (float*)(ws + 14400000);             //  1,600,000 B
    int*   totals  = (int*)  (ws + 16000000);             //  3,128 B (pad 4K)
    int*   base    = (int*)  (ws + 16004096);             //  3,132 B (pad 4K)
    int*   cursor  = (int*)  (ws + 16008192);             //  3,128 B (pad 4K)
    int*   node_off= (int*)  (ws + 16012288);             //    400,004 B
    unsigned long long* buf = (unsigned long long*)(ws + 16416768); // 25,600,000 B
                                                          // total ~42 MB

    hipMemsetAsync(totals, 0, NB * sizeof(int), stream);

    node_proj<<<1250, 256, 0, stream>>>(node_feat, Wfc, attn_l, attn_r, featb, el, er);
    bhist<<<512, 256, 0, stream>>>(dst, totals);
    bscan<<<1, 64, 0, stream>>>(totals, base, cursor);
    partition<<<NPART, 256, 0, stream>>>(src, dst, cursor, buf);
    finesort<<<NB, 256, 0, stream>>>(base, buf, node_off);
    aggregate<<<(N_NODES * 64 + 255) / 256, 256, 0, stream>>>(
        edge_feat, We, el, er, node_off, buf, featb, rst);
}

// Round 6
// 392.351 us; speedup vs baseline: 4.4521x; 1.0801x over previous
//
#include <hip/hip_runtime.h>
#include <hip/hip_fp16.h>

#define N_NODES 100000
#define N_EDGES 3200000
#define BUCKET_SHIFT 7
#define BUCKET_NODES 128
#define NB 782            // ceil(100000/128) buckets of 128 dst nodes
#define CHUNK 8192        // edges per partition block
#define NPART 391         // ceil(N_EDGES / CHUNK)
#define FS_CAP 6144       // finesort LDS capacity (mean bucket = 4096, +32 sigma)

__device__ __forceinline__ unsigned short f2bf(float f) {
    unsigned u = __float_as_uint(f);
    unsigned r = (u + 0x7FFFu + ((u >> 16) & 1u)) >> 16;   // RNE
    return (unsigned short)r;
}
__device__ __forceinline__ float bf2f(unsigned short h) {
    return __uint_as_float(((unsigned)h) << 16);
}

// ---------------------------------------------------------------------------
// Kernel A: feat(bf16) = node_feat @ Wfc.T, el/er = sum(feat*attn, -1)
// ---------------------------------------------------------------------------
__global__ __launch_bounds__(256) void node_proj(
    const float* __restrict__ node_feat,
    const float* __restrict__ Wfc,
    const float* __restrict__ attn_l,
    const float* __restrict__ attn_r,
    unsigned short* __restrict__ featb,
    float* __restrict__ el,
    float* __restrict__ er)
{
    __shared__ float T2[32 * 64 * 4];   // T2[(k4*64 + j)*4 + kk] = Wfc[j*128 + k4*4+kk]
    const int tid = threadIdx.x;
    for (int i = tid; i < 64 * 128; i += 256) {
        int j = i >> 7, k = i & 127;
        T2[((k >> 2) * 64 + j) * 4 + (k & 3)] = Wfc[i];
    }
    __syncthreads();

    const int lane = tid & 63;
    const float al = attn_l[lane];
    const float ar = attn_r[lane];
    const int gw = blockIdx.x * 4 + (tid >> 6);
    const int nw = gridDim.x * 4;
    const float4* __restrict__ T2v = (const float4*)T2;

    for (int g = gw; g * 4 < N_NODES; g += nw) {
        const int n0 = g * 4;
        const float4* __restrict__ x0 = (const float4*)(node_feat + (size_t)(n0 + 0) * 128);
        const float4* __restrict__ x1 = (const float4*)(node_feat + (size_t)(n0 + 1) * 128);
        const float4* __restrict__ x2 = (const float4*)(node_feat + (size_t)(n0 + 2) * 128);
        const float4* __restrict__ x3 = (const float4*)(node_feat + (size_t)(n0 + 3) * 128);

        float acc0 = 0.f, acc1 = 0.f, acc2 = 0.f, acc3 = 0.f;
        #pragma unroll 8
        for (int k4 = 0; k4 < 32; ++k4) {
            const float4 v0 = x0[k4], v1 = x1[k4], v2 = x2[k4], v3 = x3[k4];
            const float4 w = T2v[k4 * 64 + lane];
            acc0 = fmaf(v0.x, w.x, acc0); acc0 = fmaf(v0.y, w.y, acc0);
            acc0 = fmaf(v0.z, w.z, acc0); acc0 = fmaf(v0.w, w.w, acc0);
            acc1 = fmaf(v1.x, w.x, acc1); acc1 = fmaf(v1.y, w.y, acc1);
            acc1 = fmaf(v1.z, w.z, acc1); acc1 = fmaf(v1.w, w.w, acc1);
            acc2 = fmaf(v2.x, w.x, acc2); acc2 = fmaf(v2.y, w.y, acc2);
            acc2 = fmaf(v2.z, w.z, acc2); acc2 = fmaf(v2.w, w.w, acc2);
            acc3 = fmaf(v3.x, w.x, acc3); acc3 = fmaf(v3.y, w.y, acc3);
            acc3 = fmaf(v3.z, w.z, acc3); acc3 = fmaf(v3.w, w.w, acc3);
        }

        featb[(size_t)(n0 + 0) * 64 + lane] = f2bf(acc0);
        featb[(size_t)(n0 + 1) * 64 + lane] = f2bf(acc1);
        featb[(size_t)(n0 + 2) * 64 + lane] = f2bf(acc2);
        featb[(size_t)(n0 + 3) * 64 + lane] = f2bf(acc3);

        const float accs[4] = {acc0, acc1, acc2, acc3};
        #pragma unroll
        for (int i = 0; i < 4; ++i) {
            float vl = accs[i] * al;
            float vr = accs[i] * ar;
            #pragma unroll
            for (int off = 8; off >= 1; off >>= 1) {
                vl += __shfl_xor(vl, off);
                vr += __shfl_xor(vr, off);
            }
            if ((lane & 15) == 0) {
                el[(size_t)(n0 + i) * 4 + (lane >> 4)] = vl;
                er[(size_t)(n0 + i) * 4 + (lane >> 4)] = vr;
            }
        }
    }
}

// ---------------------------------------------------------------------------
// Bucket histogram: LDS-aggregated
// ---------------------------------------------------------------------------
__global__ __launch_bounds__(256) void bhist(const int* __restrict__ dst,
                                             int* __restrict__ totals)
{
    __shared__ int h[NB];
    for (int i = threadIdx.x; i < NB; i += 256) h[i] = 0;
    __syncthreads();
    const int stride = gridDim.x * 256;
    for (int e = blockIdx.x * 256 + threadIdx.x; e < N_EDGES; e += stride)
        atomicAdd(&h[dst[e] >> BUCKET_SHIFT], 1);
    __syncthreads();
    for (int i = threadIdx.x; i < NB; i += 256)
        if (h[i]) atomicAdd(&totals[i], h[i]);
}

// ---------------------------------------------------------------------------
// Scan of NB bucket totals: single wave, shfl scan with running carry
// ---------------------------------------------------------------------------
__global__ __launch_bounds__(64) void bscan(const int* __restrict__ totals,
                                            int* __restrict__ base,
                                            int* __restrict__ cursor)
{
    const int lane = threadIdx.x;
    int carry = 0;
    for (int ch = 0; ch < NB; ch += 64) {
        const int idx = ch + lane;
        const int v = (idx < NB) ? totals[idx] : 0;
        int x = v;
        #pragma unroll
        for (int off = 1; off < 64; off <<= 1) {
            int y = __shfl_up(x, off);
            if (lane >= off) x += y;
        }
        const int excl = x - v + carry;
        if (idx < NB) { base[idx] = excl; cursor[idx] = excl; }
        carry += __shfl(x, 63);
    }
    if (lane == 0) base[NB] = carry;
}

// ---------------------------------------------------------------------------
// Partition v2: bucket edges AND compute the whole sigma-path per edge
// (streaming edge_feat read, L2-resident el/er gathers, 1 thread = 1 edge).
// Payload: wA = src | dst_local<<17 (4 B), wB = ee[0..3] as fp16x4 (8 B).
// ---------------------------------------------------------------------------
__global__ __launch_bounds__(256) void partition(
    const int* __restrict__ src,
    const int* __restrict__ dst,
    const float* __restrict__ edge_feat,
    const float* __restrict__ We,
    const float* __restrict__ el,
    const float* __restrict__ er,
    int* __restrict__ cursor,
    unsigned* __restrict__ wA,
    uint2* __restrict__ wB)
{
    __shared__ int ldst[CHUNK];
    __shared__ int lbase[NB];
    __shared__ int lcnt[NB];
    const int e0 = blockIdx.x * CHUNK;
    const int n = min(CHUNK, N_EDGES - e0);
    for (int i = threadIdx.x; i < NB; i += 256) lcnt[i] = 0;
    __syncthreads();
    for (int i = threadIdx.x; i < n; i += 256) {
        const int d = dst[e0 + i];
        ldst[i] = d;
        atomicAdd(&lcnt[d >> BUCKET_SHIFT], 1);
    }
    __syncthreads();
    for (int b = threadIdx.x; b < NB; b += 256) {
        const int c = lcnt[b];
        lbase[b] = c ? atomicAdd(&cursor[b], c) : 0;
        lcnt[b] = 0;
    }
    __syncthreads();

    const float4 W0 = ((const float4*)We)[0];
    const float4 W1 = ((const float4*)We)[1];
    const float4 W2 = ((const float4*)We)[2];
    const float4 W3 = ((const float4*)We)[3];

    for (int i = threadIdx.x; i < n; i += 256) {
        const int d = ldst[i];
        const int b = d >> BUCKET_SHIFT;
        const int r = atomicAdd(&lcnt[b], 1);
        const int pos = lbase[b] + r;

        const int s = src[e0 + i];
        const float4 ef = ((const float4*)edge_feat)[e0 + i];
        const float4 l4 = ((const float4*)el)[s];
        const float4 r4 = ((const float4*)er)[d];

        float t0 = l4.x + r4.x; t0 = t0 > 0.f ? t0 : 0.2f * t0;
        float t1 = l4.y + r4.y; t1 = t1 > 0.f ? t1 : 0.2f * t1;
        float t2 = l4.z + r4.z; t2 = t2 > 0.f ? t2 : 0.2f * t2;
        float t3 = l4.w + r4.w; t3 = t3 > 0.f ? t3 : 0.2f * t3;

        const float ee0 = __expf(t0 * (W0.x * ef.x + W0.y * ef.y + W0.z * ef.z + W0.w * ef.w));
        const float ee1 = __expf(t1 * (W1.x * ef.x + W1.y * ef.y + W1.z * ef.z + W1.w * ef.w));
        const float ee2 = __expf(t2 * (W2.x * ef.x + W2.y * ef.y + W2.z * ef.z + W2.w * ef.w));
        const float ee3 = __expf(t3 * (W3.x * ef.x + W3.y * ef.y + W3.z * ef.z + W3.w * ef.w));

        const unsigned h0 = __half_as_ushort(__float2half_rn(ee0));
        const unsigned h1 = __half_as_ushort(__float2half_rn(ee1));
        const unsigned h2 = __half_as_ushort(__float2half_rn(ee2));
        const unsigned h3 = __half_as_ushort(__float2half_rn(ee3));

        wA[pos] = (unsigned)s | ((unsigned)(d & (BUCKET_NODES - 1)) << 17);
        wB[pos] = make_uint2(h0 | (h1 << 16), h2 | (h3 << 16));
    }
}

// ---------------------------------------------------------------------------
// Finesort: one block per bucket. Tandem counting-sort of (wA, wB) by
// dst-local IN PLACE, emit exact per-node CSR offsets. All atomics LDS.
// ---------------------------------------------------------------------------
__global__ __launch_bounds__(256) void finesort(
    const int* __restrict__ base,
    unsigned* __restrict__ wA,
    uint2* __restrict__ wB,
    int* __restrict__ node_off)
{
    __shared__ unsigned sA[FS_CAP];
    __shared__ uint2 sB[FS_CAP];
    __shared__ int hist[BUCKET_NODES];
    __shared__ int cur[BUCKET_NODES];
    const int b = blockIdx.x;
    const int s = base[b];
    int cnt = base[b + 1] - s;
    if (cnt > FS_CAP) cnt = FS_CAP;   // unreachable for this dataset; safety
    const int tid = threadIdx.x;
    if (tid < BUCKET_NODES) hist[tid] = 0;
    __syncthreads();
    for (int i = tid; i < cnt; i += 256) {
        const unsigned a = wA[s + i];
        sA[i] = a;
        sB[i] = wB[s + i];
        atomicAdd(&hist[(a >> 17) & (BUCKET_NODES - 1)], 1);
    }
    __syncthreads();
    if (tid < 64) {
        int carry = 0;
        for (int ch = 0; ch < BUCKET_NODES; ch += 64) {
            const int v = hist[ch + tid];
            int x = v;
            #pragma unroll
            for (int off = 1; off < 64; off <<= 1) {
                int y = __shfl_up(x, off);
                if (tid >= off) x += y;
            }
            const int excl = x - v + carry;
            cur[ch + tid] = excl;
            const int node = b * BUCKET_NODES + ch + tid;
            if (node < N_NODES) node_off[node] = s + excl;
            carry += __shfl(x, 63);
        }
        if (tid == 0 && b == NB - 1) node_off[N_NODES] = N_EDGES;
    }
    __syncthreads();
    for (int i = tid; i < cnt; i += 256) {
        const unsigned a = sA[i];
        const int dl = (a >> 17) & (BUCKET_NODES - 1);
        const int r = atomicAdd(&cur[dl], 1);
        wA[s + r] = a;
        wB[s + r] = sB[i];
    }
}

// ---------------------------------------------------------------------------
// Aggregate v3: one wave per dst node. Phase 1: each lane decodes its OWN
// edge's ee4 into LDS + register ssum. Phase 2 per edge: 2 ds_read + featb
// gather + 1 fma. No exp / el / edge_feat access here at all.
// ---------------------------------------------------------------------------
__global__ __launch_bounds__(256) void aggregate(
    const int* __restrict__ node_off,
    const unsigned* __restrict__ wA,
    const uint2* __restrict__ wB,
    const unsigned short* __restrict__ featb,
    float* __restrict__ rst)
{
    __shared__ float lee[4][64][4];   // [wave][edge][c]   16 KB
    __shared__ int   lsi[4][64];      //                    1 KB
    const int tid = threadIdx.x;
    const int node = (int)((blockIdx.x * 256 + tid) >> 6);
    const int lane = tid & 63;
    const int w = tid >> 6;
    if (node >= N_NODES) return;
    const int c = lane >> 4;

    const int start = node_off[node];
    const int end = node_off[node + 1];

    float acc = 0.f;
    float s0 = 0.f, s1 = 0.f, s2 = 0.f, s3 = 0.f;

    for (int bat = start; bat < end; bat += 64) {
        const int n = min(64, end - bat);
        if (lane < n) {
            const unsigned a = wA[bat + lane];
            const uint2 bb = wB[bat + lane];
            const float e0 = __half2float(__ushort_as_half((unsigned short)(bb.x & 0xffffu)));
            const float e1 = __half2float(__ushort_as_half((unsigned short)(bb.x >> 16)));
            const float e2 = __half2float(__ushort_as_half((unsigned short)(bb.y & 0xffffu)));
            const float e3 = __half2float(__ushort_as_half((unsigned short)(bb.y >> 16)));
            lsi[w][lane] = (int)(a & 0x1FFFFu);
            float4 v = make_float4(e0, e1, e2, e3);
            *(float4*)&lee[w][lane][0] = v;
            s0 += e0; s1 += e1; s2 += e2; s3 += e3;
        }
        __builtin_amdgcn_wave_barrier();   // keep LDS write->read in program order
        for (int i = 0; i < n; ++i) {
            const int si = lsi[w][i];
            const float eec = lee[w][i][c];
            const float fv = bf2f(featb[(size_t)si * 64 + lane]);
            acc = fmaf(eec, fv, acc);
        }
        __builtin_amdgcn_wave_barrier();   // WAR: next batch overwrites lee
    }

    #pragma unroll
    for (int off = 32; off >= 1; off >>= 1) {
        s0 += __shfl_xor(s0, off);
        s1 += __shfl_xor(s1, off);
        s2 += __shfl_xor(s2, off);
        s3 += __shfl_xor(s3, off);
    }
    const float ssum = (c == 0) ? s0 : ((c == 1) ? s1 : ((c == 2) ? s2 : s3));
    rst[(size_t)node * 64 + lane] = (end > start) ? acc / ssum : 0.f;
}

// ---------------------------------------------------------------------------
extern "C" void kernel_launch(void* const* d_in, const int* in_sizes, int n_in,
                              void* d_out, int out_size, void* d_ws, size_t ws_size,
                              hipStream_t stream)
{
    const float* node_feat = (const float*)d_in[0];
    const float* edge_feat = (const float*)d_in[1];
    const int*   src       = (const int*)d_in[2];
    const int*   dst       = (const int*)d_in[3];
    const float* Wfc       = (const float*)d_in[4];
    const float* We        = (const float*)d_in[5];
    const float* attn_l    = (const float*)d_in[6];
    const float* attn_r    = (const float*)d_in[7];
    float* rst = (float*)d_out;

    char* ws = (char*)d_ws;
    unsigned short* featb = (unsigned short*)(ws);        // 12,800,000 B
    float* el      = (float*)(ws + 12800000);             //  1,600,000 B
    float* er      = (float*)(ws + 14400000);             //  1,600,000 B
    int*   totals  = (int*)  (ws + 16000000);             //  3,132 B (pad 4K)
    int*   base    = (int*)  (ws + 16004096);             //  3,132 B (pad 4K)
    int*   cursor  = (int*)  (ws + 16008192);             //  3,128 B (pad 4K)
    int*   node_off= (int*)  (ws + 16012288);             //    400,004 B (pad)
    unsigned* wA   = (unsigned*)(ws + 16416768);          // 12,800,000 B
    uint2* wB      = (uint2*)(ws + 29216768);             // 25,600,000 B
                                                          // total ~54.8 MB

    hipMemsetAsync(totals, 0, NB * sizeof(int), stream);

    node_proj<<<1250, 256, 0, stream>>>(node_feat, Wfc, attn_l, attn_r, featb, el, er);
    bhist<<<512, 256, 0, stream>>>(dst, totals);
    bscan<<<1, 64, 0, stream>>>(totals, base, cursor);
    partition<<<NPART, 256, 0, stream>>>(src, dst, edge_feat, We, el, er, cursor, wA, wB);
    finesort<<<NB, 256, 0, stream>>>(base, wA, wB, node_off);
    aggregate<<<(N_NODES * 64 + 255) / 256, 256, 0, stream>>>(node_off, wA, wB, featb, rst);
}

// Round 7
// 379.277 us; speedup vs baseline: 4.6056x; 1.0345x over previous
//
#include <hip/hip_runtime.h>
#include <hip/hip_fp16.h>

#define N_NODES 100000
#define N_EDGES 3200000
#define BUCKET_SHIFT 7
#define BUCKET_NODES 128
#define NB 782            // ceil(100000/128) buckets of 128 dst nodes
#define CHUNK 2048        // edges per partition block (small => many blocks)
#define NPART 1563        // ceil(N_EDGES / CHUNK)
#define FS_CAP 4608       // finesort LDS capacity (mean bucket 4096, +8 sigma)

__device__ __forceinline__ unsigned short f2bf(float f) {
    unsigned u = __float_as_uint(f);
    unsigned r = (u + 0x7FFFu + ((u >> 16) & 1u)) >> 16;   // RNE
    return (unsigned short)r;
}
__device__ __forceinline__ float bf2f(unsigned short h) {
    return __uint_as_float(((unsigned)h) << 16);
}

// ---------------------------------------------------------------------------
// Kernel A: feat(bf16) = node_feat @ Wfc.T, el/er = sum(feat*attn, -1)
// ---------------------------------------------------------------------------
__global__ __launch_bounds__(256) void node_proj(
    const float* __restrict__ node_feat,
    const float* __restrict__ Wfc,
    const float* __restrict__ attn_l,
    const float* __restrict__ attn_r,
    unsigned short* __restrict__ featb,
    float* __restrict__ el,
    float* __restrict__ er)
{
    __shared__ float T2[32 * 64 * 4];   // T2[(k4*64 + j)*4 + kk] = Wfc[j*128 + k4*4+kk]
    const int tid = threadIdx.x;
    for (int i = tid; i < 64 * 128; i += 256) {
        int j = i >> 7, k = i & 127;
        T2[((k >> 2) * 64 + j) * 4 + (k & 3)] = Wfc[i];
    }
    __syncthreads();

    const int lane = tid & 63;
    const float al = attn_l[lane];
    const float ar = attn_r[lane];
    const int gw = blockIdx.x * 4 + (tid >> 6);
    const int nw = gridDim.x * 4;
    const float4* __restrict__ T2v = (const float4*)T2;

    for (int g = gw; g * 4 < N_NODES; g += nw) {
        const int n0 = g * 4;
        const float4* __restrict__ x0 = (const float4*)(node_feat + (size_t)(n0 + 0) * 128);
        const float4* __restrict__ x1 = (const float4*)(node_feat + (size_t)(n0 + 1) * 128);
        const float4* __restrict__ x2 = (const float4*)(node_feat + (size_t)(n0 + 2) * 128);
        const float4* __restrict__ x3 = (const float4*)(node_feat + (size_t)(n0 + 3) * 128);

        float acc0 = 0.f, acc1 = 0.f, acc2 = 0.f, acc3 = 0.f;
        #pragma unroll 8
        for (int k4 = 0; k4 < 32; ++k4) {
            const float4 v0 = x0[k4], v1 = x1[k4], v2 = x2[k4], v3 = x3[k4];
            const float4 w = T2v[k4 * 64 + lane];
            acc0 = fmaf(v0.x, w.x, acc0); acc0 = fmaf(v0.y, w.y, acc0);
            acc0 = fmaf(v0.z, w.z, acc0); acc0 = fmaf(v0.w, w.w, acc0);
            acc1 = fmaf(v1.x, w.x, acc1); acc1 = fmaf(v1.y, w.y, acc1);
            acc1 = fmaf(v1.z, w.z, acc1); acc1 = fmaf(v1.w, w.w, acc1);
            acc2 = fmaf(v2.x, w.x, acc2); acc2 = fmaf(v2.y, w.y, acc2);
            acc2 = fmaf(v2.z, w.z, acc2); acc2 = fmaf(v2.w, w.w, acc2);
            acc3 = fmaf(v3.x, w.x, acc3); acc3 = fmaf(v3.y, w.y, acc3);
            acc3 = fmaf(v3.z, w.z, acc3); acc3 = fmaf(v3.w, w.w, acc3);
        }

        featb[(size_t)(n0 + 0) * 64 + lane] = f2bf(acc0);
        featb[(size_t)(n0 + 1) * 64 + lane] = f2bf(acc1);
        featb[(size_t)(n0 + 2) * 64 + lane] = f2bf(acc2);
        featb[(size_t)(n0 + 3) * 64 + lane] = f2bf(acc3);

        const float accs[4] = {acc0, acc1, acc2, acc3};
        #pragma unroll
        for (int i = 0; i < 4; ++i) {
            float vl = accs[i] * al;
            float vr = accs[i] * ar;
            #pragma unroll
            for (int off = 8; off >= 1; off >>= 1) {
                vl += __shfl_xor(vl, off);
                vr += __shfl_xor(vr, off);
            }
            if ((lane & 15) == 0) {
                el[(size_t)(n0 + i) * 4 + (lane >> 4)] = vl;
                er[(size_t)(n0 + i) * 4 + (lane >> 4)] = vr;
            }
        }
    }
}

// ---------------------------------------------------------------------------
// Bucket histogram: LDS-aggregated
// ---------------------------------------------------------------------------
__global__ __launch_bounds__(256) void bhist(const int* __restrict__ dst,
                                             int* __restrict__ totals)
{
    __shared__ int h[NB];
    for (int i = threadIdx.x; i < NB; i += 256) h[i] = 0;
    __syncthreads();
    const int stride = gridDim.x * 256;
    for (int e = blockIdx.x * 256 + threadIdx.x; e < N_EDGES; e += stride)
        atomicAdd(&h[dst[e] >> BUCKET_SHIFT], 1);
    __syncthreads();
    for (int i = threadIdx.x; i < NB; i += 256)
        if (h[i]) atomicAdd(&totals[i], h[i]);
}

// ---------------------------------------------------------------------------
// Scan of NB bucket totals: single wave, shfl scan with running carry
// ---------------------------------------------------------------------------
__global__ __launch_bounds__(64) void bscan(const int* __restrict__ totals,
                                            int* __restrict__ base,
                                            int* __restrict__ cursor)
{
    const int lane = threadIdx.x;
    int carry = 0;
    for (int ch = 0; ch < NB; ch += 64) {
        const int idx = ch + lane;
        const int v = (idx < NB) ? totals[idx] : 0;
        int x = v;
        #pragma unroll
        for (int off = 1; off < 64; off <<= 1) {
            int y = __shfl_up(x, off);
            if (lane >= off) x += y;
        }
        const int excl = x - v + carry;
        if (idx < NB) { base[idx] = excl; cursor[idx] = excl; }
        carry += __shfl(x, 63);
    }
    if (lane == 0) base[NB] = carry;
}

// ---------------------------------------------------------------------------
// Partition v3: small chunks (2048) -> 1563 blocks, 6.3 KB LDS, high
// occupancy. Computes the whole sigma-path per edge and writes ONE packed
// 12 B payload per edge: {src | dl<<17, ee01 fp16x2, ee23 fp16x2}.
// ---------------------------------------------------------------------------
__global__ __launch_bounds__(256) void partition(
    const int* __restrict__ src,
    const int* __restrict__ dst,
    const float* __restrict__ edge_feat,
    const float* __restrict__ We,
    const float* __restrict__ el,
    const float* __restrict__ er,
    int* __restrict__ cursor,
    uint3* __restrict__ wP)
{
    __shared__ int lbase[NB];
    __shared__ int lcnt[NB];
    const int e0 = blockIdx.x * CHUNK;
    const int n = min(CHUNK, N_EDGES - e0);
    for (int i = threadIdx.x; i < NB; i += 256) lcnt[i] = 0;
    __syncthreads();
    for (int i = threadIdx.x; i < n; i += 256)
        atomicAdd(&lcnt[dst[e0 + i] >> BUCKET_SHIFT], 1);
    __syncthreads();
    for (int b = threadIdx.x; b < NB; b += 256) {
        const int c = lcnt[b];
        lbase[b] = c ? atomicAdd(&cursor[b], c) : 0;
        lcnt[b] = 0;
    }
    __syncthreads();

    const float4 W0 = ((const float4*)We)[0];
    const float4 W1 = ((const float4*)We)[1];
    const float4 W2 = ((const float4*)We)[2];
    const float4 W3 = ((const float4*)We)[3];

    for (int i = threadIdx.x; i < n; i += 256) {
        const int d = dst[e0 + i];
        const int b = d >> BUCKET_SHIFT;
        const int r = atomicAdd(&lcnt[b], 1);
        const int pos = lbase[b] + r;

        const int s = src[e0 + i];
        const float4 ef = ((const float4*)edge_feat)[e0 + i];
        const float4 l4 = ((const float4*)el)[s];
        const float4 r4 = ((const float4*)er)[d];

        float t0 = l4.x + r4.x; t0 = t0 > 0.f ? t0 : 0.2f * t0;
        float t1 = l4.y + r4.y; t1 = t1 > 0.f ? t1 : 0.2f * t1;
        float t2 = l4.z + r4.z; t2 = t2 > 0.f ? t2 : 0.2f * t2;
        float t3 = l4.w + r4.w; t3 = t3 > 0.f ? t3 : 0.2f * t3;

        const float ee0 = __expf(t0 * (W0.x * ef.x + W0.y * ef.y + W0.z * ef.z + W0.w * ef.w));
        const float ee1 = __expf(t1 * (W1.x * ef.x + W1.y * ef.y + W1.z * ef.z + W1.w * ef.w));
        const float ee2 = __expf(t2 * (W2.x * ef.x + W2.y * ef.y + W2.z * ef.z + W2.w * ef.w));
        const float ee3 = __expf(t3 * (W3.x * ef.x + W3.y * ef.y + W3.z * ef.z + W3.w * ef.w));

        const unsigned h0 = __half_as_ushort(__float2half_rn(ee0));
        const unsigned h1 = __half_as_ushort(__float2half_rn(ee1));
        const unsigned h2 = __half_as_ushort(__float2half_rn(ee2));
        const unsigned h3 = __half_as_ushort(__float2half_rn(ee3));

        wP[pos] = make_uint3((unsigned)s | ((unsigned)(d & (BUCKET_NODES - 1)) << 17),
                             h0 | (h1 << 16), h2 | (h3 << 16));
    }
}

// ---------------------------------------------------------------------------
// Finesort: one block per bucket. Counting-sort of 12 B payload by dst-local
// IN PLACE, emit exact per-node CSR offsets. All atomics LDS.
// ---------------------------------------------------------------------------
__global__ __launch_bounds__(256) void finesort(
    const int* __restrict__ base,
    uint3* __restrict__ wP,
    int* __restrict__ node_off)
{
    __shared__ uint3 sP[FS_CAP];          // 54 KB
    __shared__ int hist[BUCKET_NODES];
    __shared__ int cur[BUCKET_NODES];
    const int b = blockIdx.x;
    const int s = base[b];
    int cnt = base[b + 1] - s;
    if (cnt > FS_CAP) cnt = FS_CAP;   // unreachable for this dataset; safety
    const int tid = threadIdx.x;
    if (tid < BUCKET_NODES) hist[tid] = 0;
    __syncthreads();
    for (int i = tid; i < cnt; i += 256) {
        const uint3 p = wP[s + i];
        sP[i] = p;
        atomicAdd(&hist[(p.x >> 17) & (BUCKET_NODES - 1)], 1);
    }
    __syncthreads();
    if (tid < 64) {
        int carry = 0;
        for (int ch = 0; ch < BUCKET_NODES; ch += 64) {
            const int v = hist[ch + tid];
            int x = v;
            #pragma unroll
            for (int off = 1; off < 64; off <<= 1) {
                int y = __shfl_up(x, off);
                if (tid >= off) x += y;
            }
            const int excl = x - v + carry;
            cur[ch + tid] = excl;
            const int node = b * BUCKET_NODES + ch + tid;
            if (node < N_NODES) node_off[node] = s + excl;
            carry += __shfl(x, 63);
        }
        if (tid == 0 && b == NB - 1) node_off[N_NODES] = N_EDGES;
    }
    __syncthreads();
    for (int i = tid; i < cnt; i += 256) {
        const uint3 p = sP[i];
        const int dl = (p.x >> 17) & (BUCKET_NODES - 1);
        const int r = atomicAdd(&cur[dl], 1);
        wP[s + r] = p;
    }
}

// ---------------------------------------------------------------------------
// Aggregate: one wave per dst node. Phase 1: each lane decodes its OWN
// edge's ee4 into LDS + register ssum. Phase 2 per edge: 2 ds_read + featb
// gather + 1 fma. No exp / el / edge_feat access here at all.
// ---------------------------------------------------------------------------
__global__ __launch_bounds__(256) void aggregate(
    const int* __restrict__ node_off,
    const uint3* __restrict__ wP,
    const unsigned short* __restrict__ featb,
    float* __restrict__ rst)
{
    __shared__ float lee[4][64][4];   // [wave][edge][c]   16 KB
    __shared__ int   lsi[4][64];      //                    1 KB
    const int tid = threadIdx.x;
    const int node = (int)((blockIdx.x * 256 + tid) >> 6);
    const int lane = tid & 63;
    const int w = tid >> 6;
    if (node >= N_NODES) return;
    const int c = lane >> 4;

    const int start = node_off[node];
    const int end = node_off[node + 1];

    float acc = 0.f;
    float s0 = 0.f, s1 = 0.f, s2 = 0.f, s3 = 0.f;

    for (int bat = start; bat < end; bat += 64) {
        const int n = min(64, end - bat);
        if (lane < n) {
            const uint3 p = wP[bat + lane];
            const float e0 = __half2float(__ushort_as_half((unsigned short)(p.y & 0xffffu)));
            const float e1 = __half2float(__ushort_as_half((unsigned short)(p.y >> 16)));
            const float e2 = __half2float(__ushort_as_half((unsigned short)(p.z & 0xffffu)));
            const float e3 = __half2float(__ushort_as_half((unsigned short)(p.z >> 16)));
            lsi[w][lane] = (int)(p.x & 0x1FFFFu);
            float4 v = make_float4(e0, e1, e2, e3);
            *(float4*)&lee[w][lane][0] = v;
            s0 += e0; s1 += e1; s2 += e2; s3 += e3;
        }
        __builtin_amdgcn_wave_barrier();   // keep LDS write->read in program order
        for (int i = 0; i < n; ++i) {
            const int si = lsi[w][i];
            const float eec = lee[w][i][c];
            const float fv = bf2f(featb[(size_t)si * 64 + lane]);
            acc = fmaf(eec, fv, acc);
        }
        __builtin_amdgcn_wave_barrier();   // WAR: next batch overwrites lee
    }

    #pragma unroll
    for (int off = 32; off >= 1; off >>= 1) {
        s0 += __shfl_xor(s0, off);
        s1 += __shfl_xor(s1, off);
        s2 += __shfl_xor(s2, off);
        s3 += __shfl_xor(s3, off);
    }
    const float ssum = (c == 0) ? s0 : ((c == 1) ? s1 : ((c == 2) ? s2 : s3));
    rst[(size_t)node * 64 + lane] = (end > start) ? acc / ssum : 0.f;
}

// ---------------------------------------------------------------------------
extern "C" void kernel_launch(void* const* d_in, const int* in_sizes, int n_in,
                              void* d_out, int out_size, void* d_ws, size_t ws_size,
                              hipStream_t stream)
{
    const float* node_feat = (const float*)d_in[0];
    const float* edge_feat = (const float*)d_in[1];
    const int*   src       = (const int*)d_in[2];
    const int*   dst       = (const int*)d_in[3];
    const float* Wfc       = (const float*)d_in[4];
    const float* We        = (const float*)d_in[5];
    const float* attn_l    = (const float*)d_in[6];
    const float* attn_r    = (const float*)d_in[7];
    float* rst = (float*)d_out;

    char* ws = (char*)d_ws;
    unsigned short* featb = (unsigned short*)(ws);        // 12,800,000 B
    float* el      = (float*)(ws + 12800000);             //  1,600,000 B
    float* er      = (float*)(ws + 14400000);             //  1,600,000 B
    int*   totals  = (int*)  (ws + 16000000);             //  3,132 B (pad 4K)
    int*   base    = (int*)  (ws + 16004096);             //  3,132 B (pad 4K)
    int*   cursor  = (int*)  (ws + 16008192);             //  3,128 B (pad 4K)
    int*   node_off= (int*)  (ws + 16012288);             //    400,004 B (pad)
    uint3* wP      = (uint3*)(ws + 16416768);             // 38,400,000 B
                                                          // total ~54.8 MB

    hipMemsetAsync(totals, 0, NB * sizeof(int), stream);

    node_proj<<<1250, 256, 0, stream>>>(node_feat, Wfc, attn_l, attn_r, featb, el, er);
    bhist<<<512, 256, 0, stream>>>(dst, totals);
    bscan<<<1, 64, 0, stream>>>(totals, base, cursor);
    partition<<<NPART, 256, 0, stream>>>(src, dst, edge_feat, We, el, er, cursor, wP);
    finesort<<<NB, 256, 0, stream>>>(base, wP, node_off);
    aggregate<<<(N_NODES * 64 + 255) / 256, 256, 0, stream>>>(node_off, wP, featb, rst);
}